// Round 18
// baseline (324.308 us; speedup 1.0000x reference)
//
#include <hip/hip_runtime.h>
#include <hip/hip_bf16.h>
#include <stdint.h>

using bf16 = __hip_bfloat16;
typedef __attribute__((ext_vector_type(8))) short bf16x8;
typedef __attribute__((ext_vector_type(4))) float f32x4;
typedef __attribute__((ext_vector_type(2))) float f32x2;

#define NN 50000
#define NE 400000
#define NG 64
#define FIN 64
#define HID 96
#define CC3 64
#define NOUT 10

#define SCAN_BLOCK 256
#define NPART ((NN + SCAN_BLOCK - 1) / SCAN_BLOCK)   // 196 (<=256)
#define PBW ((112*384 + 112*512 + 64*512)/256)       // 520 weight-transpose blocks
#define ELB ((NN/16 + 3)/4)                          // 782 el1 blocks
#define DEGB ((NE + 255)/256)                        // 1563 deg blocks

__device__ __forceinline__ float b2f(bf16 h){ return __bfloat162float(h); }
__device__ __forceinline__ bf16 f2b(float f){ return __float2bfloat16(f); }
__device__ __forceinline__ float blo(unsigned v){ return __uint_as_float(v << 16); }
__device__ __forceinline__ float bhi(unsigned v){ return __uint_as_float(v & 0xFFFF0000u); }

// Swizzled WT element index: global layout == the LDS image gemm wants, so staging
// is a LINEAR copy (global_load_lds-compatible; swizzle lives in prep_b's store).
__device__ __forceinline__ size_t swzidx(int col, int k, int ncol){
  int chunk = k >> 7, kr = k & 127, sg = kr >> 3, b = kr & 7;
  unsigned byteoff = (unsigned)(sg*16) ^ (unsigned)((col & 7) << 4);
  return (size_t)chunk*ncol*128 + (size_t)col*128 + (byteoff >> 1) + b;
}

// ============ prep_a: logit folds, folded-logit tile for layer 1, zero fills ========
struct PrepA {
  const float *Wm1,*att1,*bm1,*Wm2,*att2,*bm2,*Wm3,*att3,*bm3,*bs1;
  float *f2,*f3,*lbv,*zb; bf16* WTf1;
  int* deg; float* psum; int* done;
};
__global__ __launch_bounds__(256) void prep_a_kernel(PrepA j){
  int bid = blockIdx.x;
  if (bid == 0){
    for (int i=threadIdx.x; i<96*4; i+=256){
      int k=i>>2, h=i&3; float a=0.f;
      for (int c=0;c<96;++c) a += j.Wm2[k*384 + h*96 + c]*j.att2[h*96+c];
      j.f2[i]=a;
    }
    for (int i=threadIdx.x; i<96*4; i+=256){
      int k=i>>2, h=i&3; float a=0.f;
      for (int c=0;c<64;++c) a += j.Wm3[k*256 + h*64 + c]*j.att3[h*64+c];
      j.f3[i]=a;
    }
    for (int i=threadIdx.x; i<16*64; i+=256){
      int col=i>>6, k=i&63; float a=0.f;
      if (col<4){ for (int c=0;c<96;++c) a += j.Wm1[k*384 + col*96 + c]*j.att1[col*96+c]; }
      j.WTf1[i] = f2b(a);
    }
    if (threadIdx.x < 96) j.zb[threadIdx.x] = 0.f;
    __syncthreads();
    if (threadIdx.x < 4){
      int h = threadIdx.x;
      float l1=0.f,l2=0.f,l3=0.f;
      for (int c=0;c<96;++c) l1 += j.bm1[h*96+c]*j.att1[h*96+c];
      for (int c=0;c<96;++c) l2 += j.bm2[h*96+c]*j.att2[h*96+c];
      for (int c=0;c<64;++c) l3 += j.bm3[h*64+c]*j.att3[h*64+c];
      float e2 = l2;
      for (int k=0;k<96;++k) e2 += j.bs1[k]*j.f2[k*4+h];
      j.lbv[h]=l1; j.lbv[4+h]=e2; j.lbv[8+h]=l3;
    }
  } else if (bid <= NPART){
    int i=(bid-1)*256+threadIdx.x;
    if (i<NN) j.deg[i]=0;
  } else {
    for (int i=threadIdx.x; i<NG*CC3; i+=256) j.psum[i]=0.f;
    if (threadIdx.x==0) *j.done = 0;
  }
}

// ============ prep_b: SWIZZLED weight transposes (k-major, coalesced Wm reads) ======
// + el1 blocks + deg blocks. GEMM A-row layout: [ S (4*K) | ind | pad | Hprev (K) ]
// Gather record layout: rec[n] = [ EL f32x4 (16B) | fp8 H row ].
struct PrepB {
  const float *Wm1,*bm1,*Ws1,*Wm2,*bm2,*Wm3,*bm3,*Ws3;
  const float *f2,*f3;
  bf16 *WT1,*WT2,*WT3;
  const float* x; const bf16* WTf1; const float* lbv;
  bf16* xb; uint8_t* rec1;
  const int* ei; int* deg;
};
__device__ __forceinline__ float w1full(const PrepB& j, int k, int c){
  if (k < 256) return 0.25f*j.Wm1[(k&63)*384 + (k>>6)*96 + c];
  if (k == 256) return 0.25f*(j.bm1[c]+j.bm1[96+c]+j.bm1[192+c]+j.bm1[288+c]);
  if (k < 288) return 0.f;
  return j.Ws1[(k-288)*96 + c];
}
__device__ __forceinline__ float w2full(const PrepB& j, int k, int c){
  if (k < 384){ int kk=k%96, h=k/96; return 0.25f*j.Wm2[kk*384 + h*96 + c]; }
  if (k == 384) return 0.25f*(j.bm2[c]+j.bm2[96+c]+j.bm2[192+c]+j.bm2[288+c]);
  if (k < 416) return 0.f;
  return (k-416==c) ? 1.f : 0.f;
}
__device__ __forceinline__ float w3full(const PrepB& j, int k, int c){
  if (k < 384){ int kk=k%96, h=k/96; return 0.25f*j.Wm3[kk*256 + h*64 + c]; }
  if (k == 384) return 0.25f*(j.bm3[c]+j.bm3[64+c]+j.bm3[128+c]+j.bm3[192+c]);
  if (k < 416) return 0.f;
  return j.Ws3[(k-416)*64 + c];
}
__global__ __launch_bounds__(256) void prep_b_kernel(PrepB j){
  const int bid = blockIdx.x;
  if (bid < PBW){
    // k-major / col-minor: consecutive lanes read consecutive c -> coalesced.
    int idx = bid*256 + threadIdx.x;
    if (idx < 384*112){
      int k = idx/112, col = idx - k*112;
      float v;
      if (k >= 352) v = 0.f;
      else if (col < 96) v = w1full(j,k,col);
      else if (col < 100){ int h=col-96; float a=0.f;
        #pragma unroll 8
        for (int c=0;c<96;++c) a += w1full(j,k,c)*j.f2[c*4+h]; v=a; }
      else v = 0.f;
      j.WT1[swzidx(col,k,112)] = f2b(v);
    } else if (idx < 384*112 + 512*112){
      int r = idx - 384*112;
      int k = r/112, col = r - k*112;
      float v;
      if (col < 96) v = w2full(j,k,col);
      else if (col < 100){ int h=col-96; float a=0.f;
        #pragma unroll 8
        for (int c=0;c<96;++c) a += w2full(j,k,c)*j.f3[c*4+h]; v=a; }
      else v = 0.f;
      j.WT2[swzidx(col,k,112)] = f2b(v);
    } else {
      int r = idx - 384*112 - 512*112;
      int k = r/64, col = r - k*64;
      j.WT3[swzidx(col,k,64)] = f2b(w3full(j,k,col));
    }
  } else if (bid < PBW + ELB){
    // ---- el1: xb (bf16) + record [EL1 | x8] via folded-logit MFMA ----
    const int wave = threadIdx.x>>6, lane = threadIdx.x&63;
    const int tile = (bid - PBW)*4 + wave;
    if (tile >= NN/16) return;
    const int lm = lane&15, q = lane>>4;
    const size_t row = (size_t)tile*16 + lm;
    uint8_t* rrow = j.rec1 + row*80;
    bf16x8 xf[2];
    #pragma unroll
    for (int kt=0;kt<2;++kt){
      float4 a0 = *(const float4*)(j.x + row*64 + kt*32 + q*8);
      float4 a1 = *(const float4*)(j.x + row*64 + kt*32 + q*8 + 4);
      bf16 t[8] = {f2b(a0.x),f2b(a0.y),f2b(a0.z),f2b(a0.w),
                   f2b(a1.x),f2b(a1.y),f2b(a1.z),f2b(a1.w)};
      xf[kt] = *(const bf16x8*)t;
      *(bf16x8*)(j.xb + row*64 + kt*32 + q*8) = xf[kt];
      int p0 = 0, p1 = 0;
      p0 = __builtin_amdgcn_cvt_pk_fp8_f32(a0.x, a0.y, p0, false);
      p0 = __builtin_amdgcn_cvt_pk_fp8_f32(a0.z, a0.w, p0, true);
      p1 = __builtin_amdgcn_cvt_pk_fp8_f32(a1.x, a1.y, p1, false);
      p1 = __builtin_amdgcn_cvt_pk_fp8_f32(a1.z, a1.w, p1, true);
      uint2 pk; pk.x = (unsigned)p0; pk.y = (unsigned)p1;
      *(uint2*)(rrow + 16 + kt*32 + q*8) = pk;
    }
    f32x4 acc = {};
    #pragma unroll
    for (int kt=0;kt<2;++kt){
      bf16x8 wf = *(const bf16x8*)(j.WTf1 + (size_t)lm*64 + kt*32 + q*8);
      acc = __builtin_amdgcn_mfma_f32_16x16x32_bf16(wf, xf[kt], acc, 0,0,0);
    }
    if (q==0){
      float4 e; float l;
      l=acc[0]+j.lbv[0]; l=(l>=0.f)?l:0.2f*l; e.x=__expf(fminf(fmaxf(l,-60.f),60.f));
      l=acc[1]+j.lbv[1]; l=(l>=0.f)?l:0.2f*l; e.y=__expf(fminf(fmaxf(l,-60.f),60.f));
      l=acc[2]+j.lbv[2]; l=(l>=0.f)?l:0.2f*l; e.z=__expf(fminf(fmaxf(l,-60.f),60.f));
      l=acc[3]+j.lbv[3]; l=(l>=0.f)?l:0.2f*l; e.w=__expf(fminf(fmaxf(l,-60.f),60.f));
      *(float4*)rrow = e;
    }
  } else {
    // ---- deg: depends only on prep_a's zeroing of deg ----
    int e = (bid - PBW - ELB)*256 + threadIdx.x;
    if (e < NE) atomicAdd(&j.deg[j.ei[NE + e]], 1);
  }
}

// ---------------- CSR build (separate kernels — proven, full parallelism) ----------
__global__ __launch_bounds__(256) void scan_part_kernel(const int* __restrict__ deg,
    int* __restrict__ partials, int* __restrict__ done, int* __restrict__ off){
  __shared__ int ws[4];
  __shared__ int lastflag;
  __shared__ int buf[256];
  int i = blockIdx.x*SCAN_BLOCK + threadIdx.x;
  int v = (i < NN) ? deg[i] : 0;
  int lane = threadIdx.x & 63, w = threadIdx.x >> 6;
  int s = v;
  #pragma unroll
  for (int m=1;m<64;m<<=1) s += __shfl_xor(s,m);
  if (lane==0) ws[w]=s;
  __syncthreads();
  if (threadIdx.x==0){
    int tot = ws[0]+ws[1]+ws[2]+ws[3];
    atomicExch(&partials[blockIdx.x], tot);
    __threadfence();
    int old = atomicAdd(done, 1);
    lastflag = (old == NPART-1) ? 1 : 0;
  }
  __syncthreads();
  if (lastflag){
    int t = threadIdx.x;
    int pv = (t < NPART) ? atomicAdd(&partials[t], 0) : 0;
    buf[t] = pv; __syncthreads();
    for (int st=1; st<256; st<<=1){
      int x = (t>=st) ? buf[t-st] : 0;
      __syncthreads();
      buf[t] += x;
      __syncthreads();
    }
    if (t < NPART) atomicExch(&partials[t], buf[t] - pv);
    if (t == 0) off[NN] = buf[255];
  }
}

__global__ __launch_bounds__(256) void scan_final_kernel(const int* __restrict__ deg,
    const int* __restrict__ partials, int* __restrict__ off, int* __restrict__ cursor){
  __shared__ int buf[256];
  int i = blockIdx.x*SCAN_BLOCK + threadIdx.x;
  int t = threadIdx.x;
  int v = (i<NN) ? deg[i] : 0;
  buf[t] = v; __syncthreads();
  for (int s=1;s<256;s<<=1){
    int x = (t>=s) ? buf[t-s] : 0;
    __syncthreads();
    buf[t] += x;
    __syncthreads();
  }
  int ex = partials[blockIdx.x] + buf[t] - v;
  if (i<NN){ off[i]=ex; cursor[i]=ex; }
}

__global__ void scatter_kernel(const int* __restrict__ ei, int* __restrict__ cursor,
                               int* __restrict__ csr_src){
  int e = blockIdx.x*256 + threadIdx.x;
  if (e < NE){
    int d = ei[NE + e];
    int slot = atomicAdd(&cursor[d], 1);
    csr_src[slot] = ei[e];
  }
}

// ============ agg: TWO nodes per wave (2x memory-level parallelism), zero LDS =======
// Per iteration: load both nodes' id batches, issue both nodes' row loads (<=32 in
// flight), then FMA both. Halves per-node serial round-trip cost at mean deg 8.
template<int KH, int STRIDE>
__global__ __launch_bounds__(256) void agg_kernel(
    const int* __restrict__ off, const int* __restrict__ csr_src,
    const uint8_t* __restrict__ rec, uint8_t* __restrict__ Sb)
{
  constexpr int R  = 4*KH;                  // 256 or 384
  constexpr int KS = R + 32;                // + ind + pad (bytes in fp8)
  const int wave = threadIdx.x >> 6, lane = threadIdx.x & 63;
  const int nA = blockIdx.x*8 + wave*2;
  const int nB = nA + 1;
  const int e0A = off[nA], e1A = off[nA+1];
  const int e0B = off[nB], e1B = off[nB+1];
  const int one8 = __builtin_amdgcn_cvt_pk_fp8_f32(1.f, 0.f, 0, false); // fp8 1.0 byte0

  if (KH == 64){
    const int hidx = lane >> 4;
    const int kk = (4*lane) & 63;
    float accA[4] = {0.f,0.f,0.f,0.f}, accB[4] = {0.f,0.f,0.f,0.f};
    float dnlA = 0.f, dnlB = 0.f;
    int baseA = e0A, baseB = e0B;
    while (baseA < e1A || baseB < e1B){
      const int cntA = min(8, e1A-baseA);    // may be <=0 (done)
      const int cntB = min(8, e1B-baseB);
      int srA = (cntA > 0 && lane < cntA) ? csr_src[baseA+lane] : 0;
      int srB = (cntB > 0 && lane < cntB) ? csr_src[baseB+lane] : 0;
      int svA[8], svB[8];
      #pragma unroll
      for (int j=0;j<8;++j){ svA[j] = __shfl(srA, j); svB[j] = __shfl(srB, j); }
      float wlA[8], wlB[8]; unsigned uA[8], uB[8];
      #pragma unroll
      for (int j=0;j<8;++j){                // up to 32 loads in flight
        const uint8_t* rA = rec + (size_t)svA[j]*STRIDE;
        const uint8_t* rB = rec + (size_t)svB[j]*STRIDE;
        wlA[j] = *(const float*)(rA + 4*hidx);
        uA[j]  = *(const unsigned*)(rA + 16 + kk);
        wlB[j] = *(const float*)(rB + 4*hidx);
        uB[j]  = *(const unsigned*)(rB + 16 + kk);
      }
      #pragma unroll
      for (int j=0;j<8;++j){
        float wA = (j < cntA) ? wlA[j] : 0.f;
        float wB = (j < cntB) ? wlB[j] : 0.f;
        dnlA += wA; dnlB += wB;
        f32x2 a0 = __builtin_amdgcn_cvt_pk_f32_fp8((int)uA[j], false);
        f32x2 a1 = __builtin_amdgcn_cvt_pk_f32_fp8((int)uA[j], true);
        accA[0] += a0.x*wA;  accA[1] += a0.y*wA;
        accA[2] += a1.x*wA;  accA[3] += a1.y*wA;
        f32x2 b0 = __builtin_amdgcn_cvt_pk_f32_fp8((int)uB[j], false);
        f32x2 b1 = __builtin_amdgcn_cvt_pk_f32_fp8((int)uB[j], true);
        accB[0] += b0.x*wB;  accB[1] += b0.y*wB;
        accB[2] += b1.x*wB;  accB[3] += b1.y*wB;
      }
      baseA += 8; baseB += 8;
    }
    #pragma unroll
    for (int s=0;s<2;++s){
      const float* acc = s ? accB : accA;
      const float dnl  = s ? dnlB : dnlA;
      const int n      = s ? nB : nA;
      const int e0     = s ? e0B : e0A;
      const int e1     = s ? e1B : e1A;
      const float rd = 1.f/(dnl + 1e-16f);
      uint8_t* srow = Sb + (size_t)n*KS;
      int pk = 0;
      pk = __builtin_amdgcn_cvt_pk_fp8_f32(acc[0]*rd, acc[1]*rd, pk, false);
      pk = __builtin_amdgcn_cvt_pk_fp8_f32(acc[2]*rd, acc[3]*rd, pk, true);
      *(unsigned*)(srow + hidx*64 + kk) = (unsigned)pk;
      if (lane < 8){                        // indicator + pad (bytes 256..287)
        unsigned z = 0u;
        if (lane == 0 && e1 > e0) z = (unsigned)one8;
        *(unsigned*)(srow + R + lane*4) = z;
      }
    }
  } else {
    const bool act = (8*lane) < R;
    const int hidx = min(3, (8*lane)/KH);
    const int kk = (8*lane) % KH;
    float accA[8] = {0.f,0.f,0.f,0.f,0.f,0.f,0.f,0.f};
    float accB[8] = {0.f,0.f,0.f,0.f,0.f,0.f,0.f,0.f};
    float dnlA = 0.f, dnlB = 0.f;
    int baseA = e0A, baseB = e0B;
    while (baseA < e1A || baseB < e1B){
      const int cntA = min(8, e1A-baseA);
      const int cntB = min(8, e1B-baseB);
      int srA = (cntA > 0 && lane < cntA) ? csr_src[baseA+lane] : 0;
      int srB = (cntB > 0 && lane < cntB) ? csr_src[baseB+lane] : 0;
      int svA[8], svB[8];
      #pragma unroll
      for (int j=0;j<8;++j){ svA[j] = __shfl(srA, j); svB[j] = __shfl(srB, j); }
      float wlA[8], wlB[8]; uint2 uA[8], uB[8];
      #pragma unroll
      for (int j=0;j<8;++j){                // up to 32 loads in flight
        const uint8_t* rA = rec + (size_t)svA[j]*STRIDE;
        const uint8_t* rB = rec + (size_t)svB[j]*STRIDE;
        wlA[j] = *(const float*)(rA + 4*hidx);
        uA[j]  = *(const uint2*)(rA + 16 + kk);
        wlB[j] = *(const float*)(rB + 4*hidx);
        uB[j]  = *(const uint2*)(rB + 16 + kk);
      }
      #pragma unroll
      for (int j=0;j<8;++j){
        float wA = (j < cntA) ? wlA[j] : 0.f;
        float wB = (j < cntB) ? wlB[j] : 0.f;
        dnlA += wA; dnlB += wB;
        f32x2 a0 = __builtin_amdgcn_cvt_pk_f32_fp8((int)uA[j].x, false);
        f32x2 a1 = __builtin_amdgcn_cvt_pk_f32_fp8((int)uA[j].x, true);
        f32x2 a2 = __builtin_amdgcn_cvt_pk_f32_fp8((int)uA[j].y, false);
        f32x2 a3 = __builtin_amdgcn_cvt_pk_f32_fp8((int)uA[j].y, true);
        accA[0] += a0.x*wA;  accA[1] += a0.y*wA;
        accA[2] += a1.x*wA;  accA[3] += a1.y*wA;
        accA[4] += a2.x*wA;  accA[5] += a2.y*wA;
        accA[6] += a3.x*wA;  accA[7] += a3.y*wA;
        f32x2 b0 = __builtin_amdgcn_cvt_pk_f32_fp8((int)uB[j].x, false);
        f32x2 b1 = __builtin_amdgcn_cvt_pk_f32_fp8((int)uB[j].x, true);
        f32x2 b2 = __builtin_amdgcn_cvt_pk_f32_fp8((int)uB[j].y, false);
        f32x2 b3 = __builtin_amdgcn_cvt_pk_f32_fp8((int)uB[j].y, true);
        accB[0] += b0.x*wB;  accB[1] += b0.y*wB;
        accB[2] += b1.x*wB;  accB[3] += b1.y*wB;
        accB[4] += b2.x*wB;  accB[5] += b2.y*wB;
        accB[6] += b3.x*wB;  accB[7] += b3.y*wB;
      }
      baseA += 8; baseB += 8;
    }
    #pragma unroll
    for (int s=0;s<2;++s){
      const float* acc = s ? accB : accA;
      const float dnl  = s ? dnlB : dnlA;
      const int n      = s ? nB : nA;
      const int e0     = s ? e0B : e0A;
      const int e1     = s ? e1B : e1A;
      const float rd = 1.f/(dnl + 1e-16f);
      uint8_t* srow = Sb + (size_t)n*KS;
      if (act){
        int p0 = 0, p1 = 0;
        p0 = __builtin_amdgcn_cvt_pk_fp8_f32(acc[0]*rd, acc[1]*rd, p0, false);
        p0 = __builtin_amdgcn_cvt_pk_fp8_f32(acc[2]*rd, acc[3]*rd, p0, true);
        p1 = __builtin_amdgcn_cvt_pk_fp8_f32(acc[4]*rd, acc[5]*rd, p1, false);
        p1 = __builtin_amdgcn_cvt_pk_fp8_f32(acc[6]*rd, acc[7]*rd, p1, true);
        uint2 pk; pk.x = (unsigned)p0; pk.y = (unsigned)p1;
        *(uint2*)(srow + 8*lane) = pk;
      } else if (8*lane < KS){
        uint2 z; z.x = 0u; z.y = 0u;
        if (8*lane == R && e1 > e0) z.x = (unsigned)one8;   // indicator
        *(uint2*)(srow + 8*lane) = z;
      }
    }
  }
}

// ============ gemm: 64 rows/block, hoisted A-frags (S in fp8), gload_lds staging ====
// Epilogue writes the NEXT layer's gather record [EL | H8] plus bf16 H for self rows.
template<int KH, int NCT, bool POOL>
__global__ __launch_bounds__(256, 3) void gemm_kernel(
    const uint8_t* __restrict__ Sb, const bf16* __restrict__ Hprev,
    const bf16* __restrict__ WT, const float* __restrict__ bias,
    const float* __restrict__ lbe, bf16* __restrict__ Hout,
    uint8_t* __restrict__ recOut, const int* __restrict__ batch,
    float* __restrict__ psum)
{
  constexpr int R      = 4*KH;
  constexpr int KS     = R + 32;
  constexpr int KA     = KS + KH;                 // 352 or 512
  constexpr int KTS    = KS/32;                   // 9 or 13
  constexpr int NKT    = KA/32;                   // 11 or 16
  constexpr int NCHUNK = (NKT + 3)/4;             // 3 or 4
  constexpr int NCOL   = NCT*16;                  // 112 or 64
  constexpr int NT     = NN/16;                   // 3125
  constexpr int WSZ    = NCOL*256;                // staged chunk bytes
  constexpr int OSZ    = POOL ? (4*16*68*4) : (4*16*104*2);
  constexpr int USZ    = (WSZ > OSZ) ? WSZ : OSZ;
  __shared__ __align__(16) unsigned char lds[USZ];

  const int tid  = threadIdx.x;
  const int wave = tid >> 6, lane = tid & 63;
  const int lm = lane & 15, q = lane >> 4;
  const int tile = blockIdx.x*4 + wave;
  const bool active = (tile < NT);
  const int ctile = active ? tile : (NT-1);       // clamp for safe A loads
  const size_t row = (size_t)ctile*16 + lm;

  const uint8_t* arow = Sb + row*KS;              // fp8 S row
  const bf16* hrow = Hprev + row*KH;
  const unsigned sw = (unsigned)((lm & 7) << 4);  // LDS read swizzle key

  // ---- hoisted A-fragments (land during chunk-0 staging) ----
  bf16x8 a[NKT];
  #pragma unroll
  for (int kt=0; kt<KTS; ++kt){
    uint2 s8 = *(const uint2*)(arow + kt*32 + q*8);
    f32x2 c0 = __builtin_amdgcn_cvt_pk_f32_fp8((int)s8.x, false);
    f32x2 c1 = __builtin_amdgcn_cvt_pk_f32_fp8((int)s8.x, true);
    f32x2 c2 = __builtin_amdgcn_cvt_pk_f32_fp8((int)s8.y, false);
    f32x2 c3 = __builtin_amdgcn_cvt_pk_f32_fp8((int)s8.y, true);
    bf16 t[8] = {f2b(c0.x),f2b(c0.y),f2b(c1.x),f2b(c1.y),
                 f2b(c2.x),f2b(c2.y),f2b(c3.x),f2b(c3.y)};
    a[kt] = *(const bf16x8*)t;
  }
  #pragma unroll
  for (int kt=KTS; kt<NKT; ++kt) a[kt] = *(const bf16x8*)(hrow + (kt-KTS)*32 + q*8);

  f32x4 acc[NCT];
  #pragma unroll
  for (int c=0;c<NCT;++c) acc[c] = (f32x4){0.f,0.f,0.f,0.f};

  #pragma unroll
  for (int chunk=0; chunk<NCHUNK; ++chunk){
    if (chunk) __syncthreads();                   // protect lds reuse
    // ---- stage WT chunk: linear DMA (swizzle pre-applied in global layout) ----
    {
      const char* wbase = (const char*)WT + (size_t)chunk*NCOL*256;
      #pragma unroll
      for (int it=0; it<WSZ/4096; ++it){
        const unsigned boff = (unsigned)(it*4096 + tid*16);
        __builtin_amdgcn_global_load_lds(
            (const __attribute__((address_space(1))) uint32_t*)(wbase + boff),
            (__attribute__((address_space(3))) uint32_t*)(lds + boff),
            16, 0, 0);
      }
    }
    __syncthreads();
    #pragma unroll
    for (int ct=0; ct<NCT; ++ct){
      const unsigned char* rbase = lds + (ct*16 + lm)*256;
      #pragma unroll
      for (int t=0;t<4;++t){
        const int kt = chunk*4 + t;
        if (kt < NKT){
          bf16x8 wf = *(const bf16x8*)(rbase + (((unsigned)(t*64 + q*16)) ^ sw));
          acc[ct] = __builtin_amdgcn_mfma_f32_16x16x32_bf16(wf, a[kt], acc[ct], 0,0,0);
        }
      }
    }
  }
  __syncthreads();                                // ldsw dead; obuf (aliased) live

  if (active){
    if (!POOL){
      unsigned short* ob = (unsigned short*)(lds) + wave*16*104;
      #pragma unroll
      for (int ct=0; ct<NCT-1; ++ct){
        const int c = ct*16 + q*4;
        bf16 st[4] = {f2b(acc[ct][0]+bias[c]),   f2b(acc[ct][1]+bias[c+1]),
                      f2b(acc[ct][2]+bias[c+2]), f2b(acc[ct][3]+bias[c+3])};
        *(uint2*)(ob + lm*104 + c) = *(const uint2*)st;
      }
      if (q == 0){                                // next-layer logits -> exp -> record
        float4 e; float l;
        l=acc[NCT-1][0]+lbe[0]; l=(l>=0.f)?l:0.2f*l; e.x=__expf(fminf(fmaxf(l,-60.f),60.f));
        l=acc[NCT-1][1]+lbe[1]; l=(l>=0.f)?l:0.2f*l; e.y=__expf(fminf(fmaxf(l,-60.f),60.f));
        l=acc[NCT-1][2]+lbe[2]; l=(l>=0.f)?l:0.2f*l; e.z=__expf(fminf(fmaxf(l,-60.f),60.f));
        l=acc[NCT-1][3]+lbe[3]; l=(l>=0.f)?l:0.2f*l; e.w=__expf(fminf(fmaxf(l,-60.f),60.f));
        *(float4*)(recOut + row*112) = e;
      }
      __builtin_amdgcn_wave_barrier();
      const size_t n0w = (size_t)tile*16;
      #pragma unroll
      for (int jj=0; jj<3; ++jj){                 // 16 rows x 96 cols, 16B stores
        const int idx = jj*64 + lane;
        const int r = idx/12, ch = idx - r*12;
        uint4 v = *(const uint4*)(ob + r*104 + ch*8);
        *(uint4*)(Hout + (n0w+r)*96 + ch*8) = v;
        int p0 = 0, p1 = 0;
        p0 = __builtin_amdgcn_cvt_pk_fp8_f32(blo(v.x), bhi(v.x), p0, false);
        p0 = __builtin_amdgcn_cvt_pk_fp8_f32(blo(v.y), bhi(v.y), p0, true);
        p1 = __builtin_amdgcn_cvt_pk_fp8_f32(blo(v.z), bhi(v.z), p1, false);
        p1 = __builtin_amdgcn_cvt_pk_fp8_f32(blo(v.w), bhi(v.w), p1, true);
        uint2 pk; pk.x = (unsigned)p0; pk.y = (unsigned)p1;
        *(uint2*)(recOut + (n0w+r)*112 + 16 + ch*8) = pk;
      }
    } else {
      float* ob = (float*)(lds) + wave*16*68;
      #pragma unroll
      for (int ct=0; ct<NCT; ++ct){
        const int c = ct*16 + q*4;
        float* orow = ob + lm*68;
        orow[c]   = acc[ct][0]+bias[c];   orow[c+1] = acc[ct][1]+bias[c+1];
        orow[c+2] = acc[ct][2]+bias[c+2]; orow[c+3] = acc[ct][3]+bias[c+3];
      }
      int bload = (lane < 16) ? batch[tile*16 + lane] : 0;
      __builtin_amdgcn_wave_barrier();
      const int c = lane;
      int curg = __shfl(bload, 0); float a2 = 0.f;
      #pragma unroll
      for (int i=0;i<16;++i){
        float v = ob[i*68 + c];
        int g = __shfl(bload, i);
        if (g != curg){ atomicAdd(&psum[curg*64+c], a2); a2=0.f; curg=g; }
        a2 += v;
      }
      atomicAdd(&psum[curg*64+c], a2);
    }
  }
}

// ---------------- classifier + log_softmax (unchanged) ----------------
__global__ __launch_bounds__(64) void fc_kernel(const float* __restrict__ psum,
    const int* __restrict__ batch, const float* __restrict__ Wfc,
    const float* __restrict__ bfc, float* __restrict__ out){
  int g = blockIdx.x, t = threadIdx.x;
  __shared__ int sb[2];
  if (t < 2){
    int target = g + t;
    int lo=0, hi=NN;
    while (lo<hi){ int mid=(lo+hi)>>1; if (batch[mid]<target) lo=mid+1; else hi=mid; }
    sb[t]=lo;
  }
  __syncthreads();
  float cnt = (float)(sb[1]-sb[0]);
  __shared__ float p[CC3];
  __shared__ float lg[NOUT];
  p[t] = psum[g*CC3 + t] / fmaxf(cnt, 1.0f);
  __syncthreads();
  if (t < NOUT){
    float a = bfc[t];
    for (int c=0;c<CC3;++c) a += p[c]*Wfc[c*NOUT + t];
    lg[t] = a;
  }
  __syncthreads();
  if (t < NOUT){
    float m = -INFINITY;
    #pragma unroll
    for (int i=0;i<NOUT;++i) m = fmaxf(m, lg[i]);
    float s = 0.f;
    #pragma unroll
    for (int i=0;i<NOUT;++i) s += __expf(lg[i]-m);
    out[g*NOUT + t] = lg[t] - m - __logf(s);
  }
}

extern "C" void kernel_launch(void* const* d_in, const int* in_sizes, int n_in,
                              void* d_out, int out_size, void* d_ws, size_t ws_size,
                              hipStream_t stream) {
  const float* xf    = (const float*)d_in[0];
  const int*   ei    = (const int*)d_in[1];
  const int*   batch = (const int*)d_in[2];
  const float* pWm1  = (const float*)d_in[3];
  const float* pbm1  = (const float*)d_in[4];
  const float* patt1 = (const float*)d_in[5];
  const float* pWs1  = (const float*)d_in[6];
  const float* pbs1  = (const float*)d_in[7];
  const float* pWm2  = (const float*)d_in[8];
  const float* pbm2  = (const float*)d_in[9];
  const float* patt2 = (const float*)d_in[10];
  const float* pWm3  = (const float*)d_in[11];
  const float* pbm3  = (const float*)d_in[12];
  const float* patt3 = (const float*)d_in[13];
  const float* pWs3  = (const float*)d_in[14];
  const float* pbs3  = (const float*)d_in[15];
  const float* pWfc  = (const float*)d_in[16];
  const float* pbfc  = (const float*)d_in[17];

  // ---- workspace layout ----
  char* p = (char*)d_ws;
  auto alloc = [&](size_t bytes)->char*{ char* q = p; p += (bytes + 255) & ~(size_t)255; return q; };
  int*     deg     = (int*)  alloc(NN*sizeof(int));
  int*     off     = (int*)  alloc((NN+1)*sizeof(int));
  int*     cursor  = (int*)  alloc(NN*sizeof(int));
  int*     csr_src = (int*)  alloc(NE*sizeof(int));
  int*     partials= (int*)  alloc(NPART*sizeof(int));
  int*     done    = (int*)  alloc(sizeof(int));
  bf16*    xb      = (bf16*) alloc((size_t)NN*64*sizeof(bf16));    // 6.4 MB
  uint8_t* rec1    = (uint8_t*)alloc((size_t)NN*80);               // 4.0 MB [EL1|x8]
  uint8_t* rec     = (uint8_t*)alloc((size_t)NN*112);              // 5.6 MB [EL|H8]
  bf16*    H1b     = (bf16*) alloc((size_t)NN*96*sizeof(bf16));    // 9.6 MB
  bf16*    H2b     = (bf16*) alloc((size_t)NN*96*sizeof(bf16));    // 9.6 MB
  uint8_t* Sb      = (uint8_t*)alloc((size_t)NN*416);              // 20.8 MB (fp8)
  float*   psum    = (float*)alloc((size_t)NG*CC3*sizeof(float));
  float*   f2      = (float*)alloc(96*4*sizeof(float));
  float*   f3      = (float*)alloc(96*4*sizeof(float));
  float*   lbv     = (float*)alloc(12*sizeof(float));
  float*   zb      = (float*)alloc(96*sizeof(float));
  bf16*    WTf1    = (bf16*) alloc((size_t)16*64*sizeof(bf16));
  bf16*    WT1     = (bf16*) alloc((size_t)112*384*sizeof(bf16));  // swizzled layout
  bf16*    WT2     = (bf16*) alloc((size_t)112*512*sizeof(bf16));  // swizzled layout
  bf16*    WT3     = (bf16*) alloc((size_t)64*512*sizeof(bf16));   // swizzled layout

  // ---- prologue ----
  PrepA pa;
  pa.Wm1=pWm1; pa.att1=patt1; pa.bm1=pbm1;
  pa.Wm2=pWm2; pa.att2=patt2; pa.bm2=pbm2;
  pa.Wm3=pWm3; pa.att3=patt3; pa.bm3=pbm3;
  pa.bs1=pbs1; pa.f2=f2; pa.f3=f3; pa.lbv=lbv; pa.zb=zb; pa.WTf1=WTf1;
  pa.deg=deg; pa.psum=psum; pa.done=done;
  prep_a_kernel<<<NPART+2, 256, 0, stream>>>(pa);

  PrepB pb;
  pb.Wm1=pWm1; pb.bm1=pbm1; pb.Ws1=pWs1;
  pb.Wm2=pWm2; pb.bm2=pbm2;
  pb.Wm3=pWm3; pb.bm3=pbm3; pb.Ws3=pWs3;
  pb.f2=f2; pb.f3=f3; pb.WT1=WT1; pb.WT2=WT2; pb.WT3=WT3;
  pb.x=xf; pb.WTf1=WTf1; pb.lbv=lbv; pb.xb=xb; pb.rec1=rec1;
  pb.ei=ei; pb.deg=deg;
  prep_b_kernel<<<PBW + ELB + DEGB, 256, 0, stream>>>(pb);

  // ---- CSR build (separate, fully parallel) ----
  scan_part_kernel<<<NPART, 256, 0, stream>>>(deg, partials, done, off);
  scan_final_kernel<<<NPART, 256, 0, stream>>>(deg, partials, off, cursor);
  scatter_kernel<<<(NE+255)/256, 256, 0, stream>>>(ei, cursor, csr_src);

  const int AGB = NN/8;            // 6250 blocks, 2 nodes/wave
  const int GGB = (NN/16 + 3)/4;   // 782 blocks, 64 rows/block

  // ---- layer 1 ----
  agg_kernel<64,80><<<AGB, 256, 0, stream>>>(off, csr_src, rec1, Sb);
  gemm_kernel<64,7,false><<<GGB, 256, 0, stream>>>(Sb, xb, WT1, pbs1, lbv+4,
                                                   H1b, rec, batch, psum);
  // ---- layer 2 ----
  agg_kernel<96,112><<<AGB, 256, 0, stream>>>(off, csr_src, rec, Sb);
  gemm_kernel<96,7,false><<<GGB, 256, 0, stream>>>(Sb, H1b, WT2, zb, lbv+8,
                                                   H2b, rec, batch, psum);
  // ---- layer 3 (pool fused) ----
  agg_kernel<96,112><<<AGB, 256, 0, stream>>>(off, csr_src, rec, Sb);
  gemm_kernel<96,4,true ><<<GGB, 256, 0, stream>>>(Sb, H2b, WT3, pbs3, nullptr,
                                                   nullptr, nullptr, batch, psum);

  // ---- classifier ----
  fc_kernel<<<NG, 64, 0, stream>>>(psum, batch, pWfc, pbfc, (float*)d_out);
}

// Round 19
// 306.805 us; speedup vs baseline: 1.0570x; 1.0570x over previous
//
#include <hip/hip_runtime.h>
#include <hip/hip_bf16.h>
#include <stdint.h>

using bf16 = __hip_bfloat16;
typedef __attribute__((ext_vector_type(8))) short bf16x8;
typedef __attribute__((ext_vector_type(4))) float f32x4;
typedef __attribute__((ext_vector_type(2))) float f32x2;

#define NN 50000
#define NE 400000
#define NG 64
#define FIN 64
#define HID 96
#define CC3 64
#define NOUT 10

#define SCAN_BLOCK 256
#define NPART ((NN + SCAN_BLOCK - 1) / SCAN_BLOCK)   // 196 (<=256)
#define PBW ((112*384 + 112*512 + 64*512)/256)       // 520 weight-transpose blocks
#define ELB ((NN/16 + 3)/4)                          // 782 el1 blocks
#define DEGB ((NE + 255)/256)                        // 1563 deg blocks

__device__ __forceinline__ float b2f(bf16 h){ return __bfloat162float(h); }
__device__ __forceinline__ bf16 f2b(float f){ return __float2bfloat16(f); }
__device__ __forceinline__ float blo(unsigned v){ return __uint_as_float(v << 16); }
__device__ __forceinline__ float bhi(unsigned v){ return __uint_as_float(v & 0xFFFF0000u); }

// Swizzled WT element index: global layout == the LDS image gemm wants, so staging
// is a LINEAR copy (global_load_lds-compatible; swizzle lives in prep_b's store).
__device__ __forceinline__ size_t swzidx(int col, int k, int ncol){
  int chunk = k >> 7, kr = k & 127, sg = kr >> 3, b = kr & 7;
  unsigned byteoff = (unsigned)(sg*16) ^ (unsigned)((col & 7) << 4);
  return (size_t)chunk*ncol*128 + (size_t)col*128 + (byteoff >> 1) + b;
}

// ============ prep_a: logit folds, folded-logit tile for layer 1, zero fills ========
struct PrepA {
  const float *Wm1,*att1,*bm1,*Wm2,*att2,*bm2,*Wm3,*att3,*bm3,*bs1;
  float *f2,*f3,*lbv,*zb; bf16* WTf1;
  int* deg; float* psum; int* done;
};
__global__ __launch_bounds__(256) void prep_a_kernel(PrepA j){
  int bid = blockIdx.x;
  if (bid == 0){
    for (int i=threadIdx.x; i<96*4; i+=256){
      int k=i>>2, h=i&3; float a=0.f;
      for (int c=0;c<96;++c) a += j.Wm2[k*384 + h*96 + c]*j.att2[h*96+c];
      j.f2[i]=a;
    }
    for (int i=threadIdx.x; i<96*4; i+=256){
      int k=i>>2, h=i&3; float a=0.f;
      for (int c=0;c<64;++c) a += j.Wm3[k*256 + h*64 + c]*j.att3[h*64+c];
      j.f3[i]=a;
    }
    for (int i=threadIdx.x; i<16*64; i+=256){
      int col=i>>6, k=i&63; float a=0.f;
      if (col<4){ for (int c=0;c<96;++c) a += j.Wm1[k*384 + col*96 + c]*j.att1[col*96+c]; }
      j.WTf1[i] = f2b(a);
    }
    if (threadIdx.x < 96) j.zb[threadIdx.x] = 0.f;
    __syncthreads();
    if (threadIdx.x < 4){
      int h = threadIdx.x;
      float l1=0.f,l2=0.f,l3=0.f;
      for (int c=0;c<96;++c) l1 += j.bm1[h*96+c]*j.att1[h*96+c];
      for (int c=0;c<96;++c) l2 += j.bm2[h*96+c]*j.att2[h*96+c];
      for (int c=0;c<64;++c) l3 += j.bm3[h*64+c]*j.att3[h*64+c];
      float e2 = l2;
      for (int k=0;k<96;++k) e2 += j.bs1[k]*j.f2[k*4+h];
      j.lbv[h]=l1; j.lbv[4+h]=e2; j.lbv[8+h]=l3;
    }
  } else if (bid <= NPART){
    int i=(bid-1)*256+threadIdx.x;
    if (i<NN) j.deg[i]=0;
  } else {
    for (int i=threadIdx.x; i<NG*CC3; i+=256) j.psum[i]=0.f;
    if (threadIdx.x==0) *j.done = 0;
  }
}

// ============ prep_b: SWIZZLED weight transposes (k-major, coalesced Wm reads) ======
// + el1 blocks + deg blocks. GEMM A-row layout: [ S (4*K) | ind | pad | Hprev (K) ]
// Gather record layout: rec[n] = [ EL f32x4 (16B) | fp8 H row ].
struct PrepB {
  const float *Wm1,*bm1,*Ws1,*Wm2,*bm2,*Wm3,*bm3,*Ws3;
  const float *f2,*f3;
  bf16 *WT1,*WT2,*WT3;
  const float* x; const bf16* WTf1; const float* lbv;
  bf16* xb; uint8_t* rec1;
  const int* ei; int* deg;
};
__device__ __forceinline__ float w1full(const PrepB& j, int k, int c){
  if (k < 256) return 0.25f*j.Wm1[(k&63)*384 + (k>>6)*96 + c];
  if (k == 256) return 0.25f*(j.bm1[c]+j.bm1[96+c]+j.bm1[192+c]+j.bm1[288+c]);
  if (k < 288) return 0.f;
  return j.Ws1[(k-288)*96 + c];
}
__device__ __forceinline__ float w2full(const PrepB& j, int k, int c){
  if (k < 384){ int kk=k%96, h=k/96; return 0.25f*j.Wm2[kk*384 + h*96 + c]; }
  if (k == 384) return 0.25f*(j.bm2[c]+j.bm2[96+c]+j.bm2[192+c]+j.bm2[288+c]);
  if (k < 416) return 0.f;
  return (k-416==c) ? 1.f : 0.f;
}
__device__ __forceinline__ float w3full(const PrepB& j, int k, int c){
  if (k < 384){ int kk=k%96, h=k/96; return 0.25f*j.Wm3[kk*256 + h*64 + c]; }
  if (k == 384) return 0.25f*(j.bm3[c]+j.bm3[64+c]+j.bm3[128+c]+j.bm3[192+c]);
  if (k < 416) return 0.f;
  return j.Ws3[(k-416)*64 + c];
}
__global__ __launch_bounds__(256) void prep_b_kernel(PrepB j){
  const int bid = blockIdx.x;
  if (bid < PBW){
    // k-major / col-minor: consecutive lanes read consecutive c -> coalesced.
    int idx = bid*256 + threadIdx.x;
    if (idx < 384*112){
      int k = idx/112, col = idx - k*112;
      float v;
      if (k >= 352) v = 0.f;
      else if (col < 96) v = w1full(j,k,col);
      else if (col < 100){ int h=col-96; float a=0.f;
        #pragma unroll 8
        for (int c=0;c<96;++c) a += w1full(j,k,c)*j.f2[c*4+h]; v=a; }
      else v = 0.f;
      j.WT1[swzidx(col,k,112)] = f2b(v);
    } else if (idx < 384*112 + 512*112){
      int r = idx - 384*112;
      int k = r/112, col = r - k*112;
      float v;
      if (col < 96) v = w2full(j,k,col);
      else if (col < 100){ int h=col-96; float a=0.f;
        #pragma unroll 8
        for (int c=0;c<96;++c) a += w2full(j,k,c)*j.f3[c*4+h]; v=a; }
      else v = 0.f;
      j.WT2[swzidx(col,k,112)] = f2b(v);
    } else {
      int r = idx - 384*112 - 512*112;
      int k = r/64, col = r - k*64;
      j.WT3[swzidx(col,k,64)] = f2b(w3full(j,k,col));
    }
  } else if (bid < PBW + ELB){
    // ---- el1: xb (bf16) + record [EL1 | x8] via folded-logit MFMA ----
    const int wave = threadIdx.x>>6, lane = threadIdx.x&63;
    const int tile = (bid - PBW)*4 + wave;
    if (tile >= NN/16) return;
    const int lm = lane&15, q = lane>>4;
    const size_t row = (size_t)tile*16 + lm;
    uint8_t* rrow = j.rec1 + row*80;
    bf16x8 xf[2];
    #pragma unroll
    for (int kt=0;kt<2;++kt){
      float4 a0 = *(const float4*)(j.x + row*64 + kt*32 + q*8);
      float4 a1 = *(const float4*)(j.x + row*64 + kt*32 + q*8 + 4);
      bf16 t[8] = {f2b(a0.x),f2b(a0.y),f2b(a0.z),f2b(a0.w),
                   f2b(a1.x),f2b(a1.y),f2b(a1.z),f2b(a1.w)};
      xf[kt] = *(const bf16x8*)t;
      *(bf16x8*)(j.xb + row*64 + kt*32 + q*8) = xf[kt];
      int p0 = 0, p1 = 0;
      p0 = __builtin_amdgcn_cvt_pk_fp8_f32(a0.x, a0.y, p0, false);
      p0 = __builtin_amdgcn_cvt_pk_fp8_f32(a0.z, a0.w, p0, true);
      p1 = __builtin_amdgcn_cvt_pk_fp8_f32(a1.x, a1.y, p1, false);
      p1 = __builtin_amdgcn_cvt_pk_fp8_f32(a1.z, a1.w, p1, true);
      uint2 pk; pk.x = (unsigned)p0; pk.y = (unsigned)p1;
      *(uint2*)(rrow + 16 + kt*32 + q*8) = pk;
    }
    f32x4 acc = {};
    #pragma unroll
    for (int kt=0;kt<2;++kt){
      bf16x8 wf = *(const bf16x8*)(j.WTf1 + (size_t)lm*64 + kt*32 + q*8);
      acc = __builtin_amdgcn_mfma_f32_16x16x32_bf16(wf, xf[kt], acc, 0,0,0);
    }
    if (q==0){
      float4 e; float l;
      l=acc[0]+j.lbv[0]; l=(l>=0.f)?l:0.2f*l; e.x=__expf(fminf(fmaxf(l,-60.f),60.f));
      l=acc[1]+j.lbv[1]; l=(l>=0.f)?l:0.2f*l; e.y=__expf(fminf(fmaxf(l,-60.f),60.f));
      l=acc[2]+j.lbv[2]; l=(l>=0.f)?l:0.2f*l; e.z=__expf(fminf(fmaxf(l,-60.f),60.f));
      l=acc[3]+j.lbv[3]; l=(l>=0.f)?l:0.2f*l; e.w=__expf(fminf(fmaxf(l,-60.f),60.f));
      *(float4*)rrow = e;
    }
  } else {
    // ---- deg: depends only on prep_a's zeroing of deg ----
    int e = (bid - PBW - ELB)*256 + threadIdx.x;
    if (e < NE) atomicAdd(&j.deg[j.ei[NE + e]], 1);
  }
}

// ---------------- CSR build (separate kernels — proven, full parallelism) ----------
__global__ __launch_bounds__(256) void scan_part_kernel(const int* __restrict__ deg,
    int* __restrict__ partials, int* __restrict__ done, int* __restrict__ off){
  __shared__ int ws[4];
  __shared__ int lastflag;
  __shared__ int buf[256];
  int i = blockIdx.x*SCAN_BLOCK + threadIdx.x;
  int v = (i < NN) ? deg[i] : 0;
  int lane = threadIdx.x & 63, w = threadIdx.x >> 6;
  int s = v;
  #pragma unroll
  for (int m=1;m<64;m<<=1) s += __shfl_xor(s,m);
  if (lane==0) ws[w]=s;
  __syncthreads();
  if (threadIdx.x==0){
    int tot = ws[0]+ws[1]+ws[2]+ws[3];
    atomicExch(&partials[blockIdx.x], tot);
    __threadfence();
    int old = atomicAdd(done, 1);
    lastflag = (old == NPART-1) ? 1 : 0;
  }
  __syncthreads();
  if (lastflag){
    int t = threadIdx.x;
    int pv = (t < NPART) ? atomicAdd(&partials[t], 0) : 0;
    buf[t] = pv; __syncthreads();
    for (int st=1; st<256; st<<=1){
      int x = (t>=st) ? buf[t-st] : 0;
      __syncthreads();
      buf[t] += x;
      __syncthreads();
    }
    if (t < NPART) atomicExch(&partials[t], buf[t] - pv);
    if (t == 0) off[NN] = buf[255];
  }
}

__global__ __launch_bounds__(256) void scan_final_kernel(const int* __restrict__ deg,
    const int* __restrict__ partials, int* __restrict__ off, int* __restrict__ cursor){
  __shared__ int buf[256];
  int i = blockIdx.x*SCAN_BLOCK + threadIdx.x;
  int t = threadIdx.x;
  int v = (i<NN) ? deg[i] : 0;
  buf[t] = v; __syncthreads();
  for (int s=1;s<256;s<<=1){
    int x = (t>=s) ? buf[t-s] : 0;
    __syncthreads();
    buf[t] += x;
    __syncthreads();
  }
  int ex = partials[blockIdx.x] + buf[t] - v;
  if (i<NN){ off[i]=ex; cursor[i]=ex; }
}

__global__ void scatter_kernel(const int* __restrict__ ei, int* __restrict__ cursor,
                               int* __restrict__ csr_src){
  int e = blockIdx.x*256 + threadIdx.x;
  if (e < NE){
    int d = ei[NE + e];
    int slot = atomicAdd(&cursor[d], 1);
    csr_src[slot] = ei[e];
  }
}

// ============ agg: ONE node per wave, zero LDS, id prefetch; unified gather record ===
template<int KH, int STRIDE>
__global__ __launch_bounds__(256) void agg_kernel(
    const int* __restrict__ off, const int* __restrict__ csr_src,
    const uint8_t* __restrict__ rec, uint8_t* __restrict__ Sb)
{
  constexpr int R  = 4*KH;                  // 256 or 384
  constexpr int KS = R + 32;                // + ind + pad (bytes in fp8)
  const int wave = threadIdx.x >> 6, lane = threadIdx.x & 63;
  const int n = blockIdx.x*4 + wave;
  const int e0 = off[n], e1 = off[n+1];
  const int one8 = __builtin_amdgcn_cvt_pk_fp8_f32(1.f, 0.f, 0, false); // fp8 1.0 byte0

  if (KH == 64){
    const int hidx = lane >> 4;
    const int kk = (4*lane) & 63;
    float acc[4] = {0.f,0.f,0.f,0.f};
    float dnl = 0.f;
    int base = e0;
    int cnt  = min(8, e1-base);
    int sreg = (base < e1 && lane < cnt) ? csr_src[base+lane] : 0;
    while (base < e1){
      const int nbase = base + 8;
      const int ncnt  = min(8, e1-nbase);
      int nreg = (nbase < e1 && lane < ncnt) ? csr_src[nbase+lane] : 0;  // prefetch
      int sv[8];
      #pragma unroll
      for (int j=0;j<8;++j) sv[j] = __shfl(sreg, j);
      float wl[8]; unsigned u[8];
      #pragma unroll
      for (int j=0;j<8;++j){                // 16 loads in flight, same record lines
        const uint8_t* rr = rec + (size_t)sv[j]*STRIDE;
        wl[j] = *(const float*)(rr + 4*hidx);
        u[j]  = *(const unsigned*)(rr + 16 + kk);
      }
      #pragma unroll
      for (int j=0;j<8;++j){
        float w = (j < cnt) ? wl[j] : 0.f;
        dnl += w;
        f32x2 a0 = __builtin_amdgcn_cvt_pk_f32_fp8((int)u[j], false);
        f32x2 a1 = __builtin_amdgcn_cvt_pk_f32_fp8((int)u[j], true);
        acc[0] += a0.x*w;  acc[1] += a0.y*w;
        acc[2] += a1.x*w;  acc[3] += a1.y*w;
      }
      sreg = nreg; cnt = ncnt; base = nbase;
    }
    const float rd = 1.f/(dnl + 1e-16f);
    uint8_t* srow = Sb + (size_t)n*KS;
    int pk = 0;
    pk = __builtin_amdgcn_cvt_pk_fp8_f32(acc[0]*rd, acc[1]*rd, pk, false);
    pk = __builtin_amdgcn_cvt_pk_fp8_f32(acc[2]*rd, acc[3]*rd, pk, true);
    *(unsigned*)(srow + hidx*64 + kk) = (unsigned)pk;
    if (lane < 8){                          // indicator + pad (bytes 256..287)
      unsigned z = 0u;
      if (lane == 0 && e1 > e0) z = (unsigned)one8;
      *(unsigned*)(srow + R + lane*4) = z;
    }
  } else {
    const bool act = (8*lane) < R;
    const int hidx = min(3, (8*lane)/KH);
    const int kk = (8*lane) % KH;
    float acc[8] = {0.f,0.f,0.f,0.f,0.f,0.f,0.f,0.f};
    float dnl = 0.f;
    int base = e0;
    int cnt  = min(8, e1-base);
    int sreg = (base < e1 && lane < cnt) ? csr_src[base+lane] : 0;
    while (base < e1){
      const int nbase = base + 8;
      const int ncnt  = min(8, e1-nbase);
      int nreg = (nbase < e1 && lane < ncnt) ? csr_src[nbase+lane] : 0;  // prefetch
      int sv[8];
      #pragma unroll
      for (int j=0;j<8;++j) sv[j] = __shfl(sreg, j);
      float wl[8]; uint2 u[8];
      #pragma unroll
      for (int j=0;j<8;++j){                // 16 loads in flight, same record lines
        const uint8_t* rr = rec + (size_t)sv[j]*STRIDE;
        wl[j] = *(const float*)(rr + 4*hidx);
        u[j]  = *(const uint2*)(rr + 16 + kk);
      }
      #pragma unroll
      for (int j=0;j<8;++j){
        float w = (j < cnt) ? wl[j] : 0.f;
        dnl += w;
        f32x2 a0 = __builtin_amdgcn_cvt_pk_f32_fp8((int)u[j].x, false);
        f32x2 a1 = __builtin_amdgcn_cvt_pk_f32_fp8((int)u[j].x, true);
        f32x2 a2 = __builtin_amdgcn_cvt_pk_f32_fp8((int)u[j].y, false);
        f32x2 a3 = __builtin_amdgcn_cvt_pk_f32_fp8((int)u[j].y, true);
        acc[0] += a0.x*w;  acc[1] += a0.y*w;
        acc[2] += a1.x*w;  acc[3] += a1.y*w;
        acc[4] += a2.x*w;  acc[5] += a2.y*w;
        acc[6] += a3.x*w;  acc[7] += a3.y*w;
      }
      sreg = nreg; cnt = ncnt; base = nbase;
    }
    const float rd = 1.f/(dnl + 1e-16f);
    uint8_t* srow = Sb + (size_t)n*KS;
    if (act){
      int p0 = 0, p1 = 0;
      p0 = __builtin_amdgcn_cvt_pk_fp8_f32(acc[0]*rd, acc[1]*rd, p0, false);
      p0 = __builtin_amdgcn_cvt_pk_fp8_f32(acc[2]*rd, acc[3]*rd, p0, true);
      p1 = __builtin_amdgcn_cvt_pk_fp8_f32(acc[4]*rd, acc[5]*rd, p1, false);
      p1 = __builtin_amdgcn_cvt_pk_fp8_f32(acc[6]*rd, acc[7]*rd, p1, true);
      uint2 pk; pk.x = (unsigned)p0; pk.y = (unsigned)p1;
      *(uint2*)(srow + 8*lane) = pk;
    } else if (8*lane < KS){
      uint2 z; z.x = 0u; z.y = 0u;
      if (8*lane == R && e1 > e0) z.x = (unsigned)one8;   // indicator
      *(uint2*)(srow + 8*lane) = z;
    }
  }
}

// ============ gemm: 64 rows/block, hoisted A-frags (S in fp8), gload_lds staging ====
// Epilogue writes the NEXT layer's gather record [EL | H8] plus bf16 H for self rows.
template<int KH, int NCT, bool POOL>
__global__ __launch_bounds__(256, 3) void gemm_kernel(
    const uint8_t* __restrict__ Sb, const bf16* __restrict__ Hprev,
    const bf16* __restrict__ WT, const float* __restrict__ bias,
    const float* __restrict__ lbe, bf16* __restrict__ Hout,
    uint8_t* __restrict__ recOut, const int* __restrict__ batch,
    float* __restrict__ psum)
{
  constexpr int R      = 4*KH;
  constexpr int KS     = R + 32;
  constexpr int KA     = KS + KH;                 // 352 or 512
  constexpr int KTS    = KS/32;                   // 9 or 13
  constexpr int NKT    = KA/32;                   // 11 or 16
  constexpr int NCHUNK = (NKT + 3)/4;             // 3 or 4
  constexpr int NCOL   = NCT*16;                  // 112 or 64
  constexpr int NT     = NN/16;                   // 3125
  constexpr int WSZ    = NCOL*256;                // staged chunk bytes
  constexpr int OSZ    = POOL ? (4*16*68*4) : (4*16*104*2);
  constexpr int USZ    = (WSZ > OSZ) ? WSZ : OSZ;
  __shared__ __align__(16) unsigned char lds[USZ];

  const int tid  = threadIdx.x;
  const int wave = tid >> 6, lane = tid & 63;
  const int lm = lane & 15, q = lane >> 4;
  const int tile = blockIdx.x*4 + wave;
  const bool active = (tile < NT);
  const int ctile = active ? tile : (NT-1);       // clamp for safe A loads
  const size_t row = (size_t)ctile*16 + lm;

  const uint8_t* arow = Sb + row*KS;              // fp8 S row
  const bf16* hrow = Hprev + row*KH;
  const unsigned sw = (unsigned)((lm & 7) << 4);  // LDS read swizzle key

  // ---- hoisted A-fragments (land during chunk-0 staging) ----
  bf16x8 a[NKT];
  #pragma unroll
  for (int kt=0; kt<KTS; ++kt){
    uint2 s8 = *(const uint2*)(arow + kt*32 + q*8);
    f32x2 c0 = __builtin_amdgcn_cvt_pk_f32_fp8((int)s8.x, false);
    f32x2 c1 = __builtin_amdgcn_cvt_pk_f32_fp8((int)s8.x, true);
    f32x2 c2 = __builtin_amdgcn_cvt_pk_f32_fp8((int)s8.y, false);
    f32x2 c3 = __builtin_amdgcn_cvt_pk_f32_fp8((int)s8.y, true);
    bf16 t[8] = {f2b(c0.x),f2b(c0.y),f2b(c1.x),f2b(c1.y),
                 f2b(c2.x),f2b(c2.y),f2b(c3.x),f2b(c3.y)};
    a[kt] = *(const bf16x8*)t;
  }
  #pragma unroll
  for (int kt=KTS; kt<NKT; ++kt) a[kt] = *(const bf16x8*)(hrow + (kt-KTS)*32 + q*8);

  f32x4 acc[NCT];
  #pragma unroll
  for (int c=0;c<NCT;++c) acc[c] = (f32x4){0.f,0.f,0.f,0.f};

  #pragma unroll
  for (int chunk=0; chunk<NCHUNK; ++chunk){
    if (chunk) __syncthreads();                   // protect lds reuse
    // ---- stage WT chunk: linear DMA (swizzle pre-applied in global layout) ----
    {
      const char* wbase = (const char*)WT + (size_t)chunk*NCOL*256;
      #pragma unroll
      for (int it=0; it<WSZ/4096; ++it){
        const unsigned boff = (unsigned)(it*4096 + tid*16);
        __builtin_amdgcn_global_load_lds(
            (const __attribute__((address_space(1))) uint32_t*)(wbase + boff),
            (__attribute__((address_space(3))) uint32_t*)(lds + boff),
            16, 0, 0);
      }
    }
    __syncthreads();
    #pragma unroll
    for (int ct=0; ct<NCT; ++ct){
      const unsigned char* rbase = lds + (ct*16 + lm)*256;
      #pragma unroll
      for (int t=0;t<4;++t){
        const int kt = chunk*4 + t;
        if (kt < NKT){
          bf16x8 wf = *(const bf16x8*)(rbase + (((unsigned)(t*64 + q*16)) ^ sw));
          acc[ct] = __builtin_amdgcn_mfma_f32_16x16x32_bf16(wf, a[kt], acc[ct], 0,0,0);
        }
      }
    }
  }
  __syncthreads();                                // ldsw dead; obuf (aliased) live

  if (active){
    if (!POOL){
      unsigned short* ob = (unsigned short*)(lds) + wave*16*104;
      #pragma unroll
      for (int ct=0; ct<NCT-1; ++ct){
        const int c = ct*16 + q*4;
        bf16 st[4] = {f2b(acc[ct][0]+bias[c]),   f2b(acc[ct][1]+bias[c+1]),
                      f2b(acc[ct][2]+bias[c+2]), f2b(acc[ct][3]+bias[c+3])};
        *(uint2*)(ob + lm*104 + c) = *(const uint2*)st;
      }
      if (q == 0){                                // next-layer logits -> exp -> record
        float4 e; float l;
        l=acc[NCT-1][0]+lbe[0]; l=(l>=0.f)?l:0.2f*l; e.x=__expf(fminf(fmaxf(l,-60.f),60.f));
        l=acc[NCT-1][1]+lbe[1]; l=(l>=0.f)?l:0.2f*l; e.y=__expf(fminf(fmaxf(l,-60.f),60.f));
        l=acc[NCT-1][2]+lbe[2]; l=(l>=0.f)?l:0.2f*l; e.z=__expf(fminf(fmaxf(l,-60.f),60.f));
        l=acc[NCT-1][3]+lbe[3]; l=(l>=0.f)?l:0.2f*l; e.w=__expf(fminf(fmaxf(l,-60.f),60.f));
        *(float4*)(recOut + row*112) = e;
      }
      __builtin_amdgcn_wave_barrier();
      const size_t n0w = (size_t)tile*16;
      #pragma unroll
      for (int jj=0; jj<3; ++jj){                 // 16 rows x 96 cols, 16B stores
        const int idx = jj*64 + lane;
        const int r = idx/12, ch = idx - r*12;
        uint4 v = *(const uint4*)(ob + r*104 + ch*8);
        *(uint4*)(Hout + (n0w+r)*96 + ch*8) = v;
        int p0 = 0, p1 = 0;
        p0 = __builtin_amdgcn_cvt_pk_fp8_f32(blo(v.x), bhi(v.x), p0, false);
        p0 = __builtin_amdgcn_cvt_pk_fp8_f32(blo(v.y), bhi(v.y), p0, true);
        p1 = __builtin_amdgcn_cvt_pk_fp8_f32(blo(v.z), bhi(v.z), p1, false);
        p1 = __builtin_amdgcn_cvt_pk_fp8_f32(blo(v.w), bhi(v.w), p1, true);
        uint2 pk; pk.x = (unsigned)p0; pk.y = (unsigned)p1;
        *(uint2*)(recOut + (n0w+r)*112 + 16 + ch*8) = pk;
      }
    } else {
      float* ob = (float*)(lds) + wave*16*68;
      #pragma unroll
      for (int ct=0; ct<NCT; ++ct){
        const int c = ct*16 + q*4;
        float* orow = ob + lm*68;
        orow[c]   = acc[ct][0]+bias[c];   orow[c+1] = acc[ct][1]+bias[c+1];
        orow[c+2] = acc[ct][2]+bias[c+2]; orow[c+3] = acc[ct][3]+bias[c+3];
      }
      int bload = (lane < 16) ? batch[tile*16 + lane] : 0;
      __builtin_amdgcn_wave_barrier();
      const int c = lane;
      int curg = __shfl(bload, 0); float a2 = 0.f;
      #pragma unroll
      for (int i=0;i<16;++i){
        float v = ob[i*68 + c];
        int g = __shfl(bload, i);
        if (g != curg){ atomicAdd(&psum[curg*64+c], a2); a2=0.f; curg=g; }
        a2 += v;
      }
      atomicAdd(&psum[curg*64+c], a2);
    }
  }
}

// ---------------- classifier + log_softmax (unchanged) ----------------
__global__ __launch_bounds__(64) void fc_kernel(const float* __restrict__ psum,
    const int* __restrict__ batch, const float* __restrict__ Wfc,
    const float* __restrict__ bfc, float* __restrict__ out){
  int g = blockIdx.x, t = threadIdx.x;
  __shared__ int sb[2];
  if (t < 2){
    int target = g + t;
    int lo=0, hi=NN;
    while (lo<hi){ int mid=(lo+hi)>>1; if (batch[mid]<target) lo=mid+1; else hi=mid; }
    sb[t]=lo;
  }
  __syncthreads();
  float cnt = (float)(sb[1]-sb[0]);
  __shared__ float p[CC3];
  __shared__ float lg[NOUT];
  p[t] = psum[g*CC3 + t] / fmaxf(cnt, 1.0f);
  __syncthreads();
  if (t < NOUT){
    float a = bfc[t];
    for (int c=0;c<CC3;++c) a += p[c]*Wfc[c*NOUT + t];
    lg[t] = a;
  }
  __syncthreads();
  if (t < NOUT){
    float m = -INFINITY;
    #pragma unroll
    for (int i=0;i<NOUT;++i) m = fmaxf(m, lg[i]);
    float s = 0.f;
    #pragma unroll
    for (int i=0;i<NOUT;++i) s += __expf(lg[i]-m);
    out[g*NOUT + t] = lg[t] - m - __logf(s);
  }
}

extern "C" void kernel_launch(void* const* d_in, const int* in_sizes, int n_in,
                              void* d_out, int out_size, void* d_ws, size_t ws_size,
                              hipStream_t stream) {
  const float* xf    = (const float*)d_in[0];
  const int*   ei    = (const int*)d_in[1];
  const int*   batch = (const int*)d_in[2];
  const float* pWm1  = (const float*)d_in[3];
  const float* pbm1  = (const float*)d_in[4];
  const float* patt1 = (const float*)d_in[5];
  const float* pWs1  = (const float*)d_in[6];
  const float* pbs1  = (const float*)d_in[7];
  const float* pWm2  = (const float*)d_in[8];
  const float* pbm2  = (const float*)d_in[9];
  const float* patt2 = (const float*)d_in[10];
  const float* pWm3  = (const float*)d_in[11];
  const float* pbm3  = (const float*)d_in[12];
  const float* patt3 = (const float*)d_in[13];
  const float* pWs3  = (const float*)d_in[14];
  const float* pbs3  = (const float*)d_in[15];
  const float* pWfc  = (const float*)d_in[16];
  const float* pbfc  = (const float*)d_in[17];

  // ---- workspace layout ----
  char* p = (char*)d_ws;
  auto alloc = [&](size_t bytes)->char*{ char* q = p; p += (bytes + 255) & ~(size_t)255; return q; };
  int*     deg     = (int*)  alloc(NN*sizeof(int));
  int*     off     = (int*)  alloc((NN+1)*sizeof(int));
  int*     cursor  = (int*)  alloc(NN*sizeof(int));
  int*     csr_src = (int*)  alloc(NE*sizeof(int));
  int*     partials= (int*)  alloc(NPART*sizeof(int));
  int*     done    = (int*)  alloc(sizeof(int));
  bf16*    xb      = (bf16*) alloc((size_t)NN*64*sizeof(bf16));    // 6.4 MB
  uint8_t* rec1    = (uint8_t*)alloc((size_t)NN*80);               // 4.0 MB [EL1|x8]
  uint8_t* rec     = (uint8_t*)alloc((size_t)NN*112);              // 5.6 MB [EL|H8]
  bf16*    H1b     = (bf16*) alloc((size_t)NN*96*sizeof(bf16));    // 9.6 MB
  bf16*    H2b     = (bf16*) alloc((size_t)NN*96*sizeof(bf16));    // 9.6 MB
  uint8_t* Sb      = (uint8_t*)alloc((size_t)NN*416);              // 20.8 MB (fp8)
  float*   psum    = (float*)alloc((size_t)NG*CC3*sizeof(float));
  float*   f2      = (float*)alloc(96*4*sizeof(float));
  float*   f3      = (float*)alloc(96*4*sizeof(float));
  float*   lbv     = (float*)alloc(12*sizeof(float));
  float*   zb      = (float*)alloc(96*sizeof(float));
  bf16*    WTf1    = (bf16*) alloc((size_t)16*64*sizeof(bf16));
  bf16*    WT1     = (bf16*) alloc((size_t)112*384*sizeof(bf16));  // swizzled layout
  bf16*    WT2     = (bf16*) alloc((size_t)112*512*sizeof(bf16));  // swizzled layout
  bf16*    WT3     = (bf16*) alloc((size_t)64*512*sizeof(bf16));   // swizzled layout

  // ---- prologue ----
  PrepA pa;
  pa.Wm1=pWm1; pa.att1=patt1; pa.bm1=pbm1;
  pa.Wm2=pWm2; pa.att2=patt2; pa.bm2=pbm2;
  pa.Wm3=pWm3; pa.att3=patt3; pa.bm3=pbm3;
  pa.bs1=pbs1; pa.f2=f2; pa.f3=f3; pa.lbv=lbv; pa.zb=zb; pa.WTf1=WTf1;
  pa.deg=deg; pa.psum=psum; pa.done=done;
  prep_a_kernel<<<NPART+2, 256, 0, stream>>>(pa);

  PrepB pb;
  pb.Wm1=pWm1; pb.bm1=pbm1; pb.Ws1=pWs1;
  pb.Wm2=pWm2; pb.bm2=pbm2;
  pb.Wm3=pWm3; pb.bm3=pbm3; pb.Ws3=pWs3;
  pb.f2=f2; pb.f3=f3; pb.WT1=WT1; pb.WT2=WT2; pb.WT3=WT3;
  pb.x=xf; pb.WTf1=WTf1; pb.lbv=lbv; pb.xb=xb; pb.rec1=rec1;
  pb.ei=ei; pb.deg=deg;
  prep_b_kernel<<<PBW + ELB + DEGB, 256, 0, stream>>>(pb);

  // ---- CSR build (separate, fully parallel) ----
  scan_part_kernel<<<NPART, 256, 0, stream>>>(deg, partials, done, off);
  scan_final_kernel<<<NPART, 256, 0, stream>>>(deg, partials, off, cursor);
  scatter_kernel<<<(NE+255)/256, 256, 0, stream>>>(ei, cursor, csr_src);

  const int AGB = NN/4;            // 12500 blocks, 1 node/wave
  const int GGB = (NN/16 + 3)/4;   // 782 blocks, 64 rows/block

  // ---- layer 1 ----
  agg_kernel<64,80><<<AGB, 256, 0, stream>>>(off, csr_src, rec1, Sb);
  gemm_kernel<64,7,false><<<GGB, 256, 0, stream>>>(Sb, xb, WT1, pbs1, lbv+4,
                                                   H1b, rec, batch, psum);
  // ---- layer 2 ----
  agg_kernel<96,112><<<AGB, 256, 0, stream>>>(off, csr_src, rec, Sb);
  gemm_kernel<96,7,false><<<GGB, 256, 0, stream>>>(Sb, H1b, WT2, zb, lbv+8,
                                                   H2b, rec, batch, psum);
  // ---- layer 3 (pool fused) ----
  agg_kernel<96,112><<<AGB, 256, 0, stream>>>(off, csr_src, rec, Sb);
  gemm_kernel<96,4,true ><<<GGB, 256, 0, stream>>>(Sb, H2b, WT3, pbs3, nullptr,
                                                   nullptr, nullptr, batch, psum);

  // ---- classifier ----
  fc_kernel<<<NG, 64, 0, stream>>>(psum, batch, pWfc, pbfc, (float*)d_out);
}